// Round 8
// baseline (245.880 us; speedup 1.0000x reference)
//
#include <hip/hip_runtime.h>
#include <hip/hip_bf16.h>
#include <math.h>

#define NB 16384
#define MED 1000
#define MD 100000          // diag table rows
#define MP 50000           // proc table rows
#define TDB 512            // blocks striding Td chunks
#define TPB 256            // blocks striding Tp chunks
#define CD 3125            // 100000/32 row-chunks
#define CP 1563            // ceil(50000/32)
#define NCV 1280           // convert blocks: (65536+262144)/256
#define FP8_SCALE 4096.0f
#define FP8_INV   (1.0f / 4096.0f)

typedef __bf16 bf16x8 __attribute__((ext_vector_type(8)));
typedef float  f32x4  __attribute__((ext_vector_type(4)));
typedef float  f32x2  __attribute__((ext_vector_type(2)));
typedef unsigned short u16;
typedef unsigned int   u32;
typedef unsigned char  u8;

__device__ __forceinline__ u16 f2bf(float f) {
    union { float f; u32 u; } v; v.f = f;
    u32 r = v.u + 0x7fffu + ((v.u >> 16) & 1u);   // RNE
    return (u16)(r >> 16);
}
__device__ __forceinline__ u32 fbits(float f) { union { float f; u32 u; } v; v.f = f; return v.u; }

// truncation-pack two fp32 -> two bf16 in one u32 (1 shift + 1 and + 1 or)
__device__ __forceinline__ u32 pktr(float lo, float hi) {
    return (fbits(lo) >> 16) | (fbits(hi) & 0xffff0000u);
}
// float4 pair -> bf16x8 frag by truncation
__device__ __forceinline__ bf16x8 pk8(const float4 a, const float4 b) {
    union { u32 u[4]; bf16x8 v; } r;
    r.u[0] = pktr(a.x, a.y); r.u[1] = pktr(a.z, a.w);
    r.u[2] = pktr(b.x, b.y); r.u[3] = pktr(b.z, b.w);
    return r.v;
}

// ---------------------------------------------------------------------------
// prep: T_d = fp8( E_d @ W1[:, :128]^T * 4096 ), T_p likewise with W1[:,128:].
// W1-resident: wave holds 64 out-cols x K=128 of W1 as A-frags (RNE bf16).
// Streams E rows (B-frags, trunc bf16) in a rolled grid-stride loop with
// 1-iteration prefetch. No LDS. C/D: col(lane&15)=table row,
// row(quad*4+r)=out-col -> 4 consecutive out-cols pack into one fp8 dword.
// Tail blocks convert W2/W3 -> bf16 (W3 zero-padded to 1024 rows).
// ---------------------------------------------------------------------------
__global__ __launch_bounds__(256, 2) void prep_kernel(
    const float* __restrict__ Ed, const float* __restrict__ Ep,
    const float* __restrict__ W1,
    const float* __restrict__ W2, const float* __restrict__ W3,
    u8* __restrict__ Td, u8* __restrict__ Tp,
    u16* __restrict__ W2b, u16* __restrict__ W3b)
{
    const int bid = blockIdx.x, tid = threadIdx.x;

    if (bid >= TDB + TPB) {             // ---- weight convert blocks ----
        int i = (bid - (TDB + TPB)) * 256 + tid;
        if (i < 65536) { W2b[i] = f2bf(W2[i]); return; }
        i -= 65536;
        if (i < 262144) W3b[i] = (i < MED * 256) ? f2bf(W3[i]) : (u16)0;
        return;
    }

    const float* E; u8* T; int M, koff, c0, nblk, nch;
    if (bid < TDB) { E = Ed; T = Td; M = MD; koff = 0;   c0 = bid;       nblk = TDB; nch = CD; }
    else           { E = Ep; T = Tp; M = MP; koff = 128; c0 = bid - TDB; nblk = TPB; nch = CP; }

    const int wave = tid >> 6, lane = tid & 63;
    const int quad = lane >> 4, l16 = lane & 15;
    const int colBase = (wave & 1) * 64;       // out-col base for this wave
    const int rowOff  = (wave >> 1) * 16;      // row sub-chunk within 32

    // ---- A-frags: W1 slice resident in registers (RNE bf16) ----
    bf16x8 a[4][4];
    #pragma unroll
    for (int mt = 0; mt < 4; ++mt) {
        const float* wp = W1 + (size_t)(colBase + mt * 16 + l16) * 256 + koff + quad * 8;
        #pragma unroll
        for (int ks = 0; ks < 4; ++ks) {
            const float4 lo = *(const float4*)(wp + ks * 32);
            const float4 hi = *(const float4*)(wp + ks * 32 + 4);
            union { u16 s[8]; bf16x8 v; } r;
            r.s[0]=f2bf(lo.x); r.s[1]=f2bf(lo.y); r.s[2]=f2bf(lo.z); r.s[3]=f2bf(lo.w);
            r.s[4]=f2bf(hi.x); r.s[5]=f2bf(hi.y); r.s[6]=f2bf(hi.z); r.s[7]=f2bf(hi.w);
            a[mt][ks] = r.v;
        }
    }

    // ---- rolled M-loop with 1-iter prefetch ----
    float4 cur[8];
    {
        const int row = min(c0 * 32 + rowOff + l16, M - 1);
        const float* p = E + (size_t)row * 128 + quad * 8;
        #pragma unroll
        for (int ks = 0; ks < 4; ++ks) {
            cur[ks * 2]     = *(const float4*)(p + ks * 32);
            cur[ks * 2 + 1] = *(const float4*)(p + ks * 32 + 4);
        }
    }

    #pragma unroll 1
    for (int c = c0; c < nch; c += nblk) {
        float4 nxt[8];
        const int cn = c + nblk;
        if (cn < nch) {
            const int row = min(cn * 32 + rowOff + l16, M - 1);
            const float* p = E + (size_t)row * 128 + quad * 8;
            #pragma unroll
            for (int ks = 0; ks < 4; ++ks) {
                nxt[ks * 2]     = *(const float4*)(p + ks * 32);
                nxt[ks * 2 + 1] = *(const float4*)(p + ks * 32 + 4);
            }
        }

        bf16x8 b[4];
        #pragma unroll
        for (int ks = 0; ks < 4; ++ks) b[ks] = pk8(cur[ks * 2], cur[ks * 2 + 1]);

        f32x4 acc[4];
        #pragma unroll
        for (int mt = 0; mt < 4; ++mt) acc[mt] = (f32x4){0.f, 0.f, 0.f, 0.f};
        #pragma unroll
        for (int ks = 0; ks < 4; ++ks)
            #pragma unroll
            for (int mt = 0; mt < 4; ++mt)
                acc[mt] = __builtin_amdgcn_mfma_f32_16x16x32_bf16(a[mt][ks], b[ks], acc[mt], 0, 0, 0);

        const int row = c * 32 + rowOff + l16;
        if (row < M) {
            u8* rp = T + (size_t)row * 128 + colBase + quad * 4;
            #pragma unroll
            for (int mt = 0; mt < 4; ++mt) {
                const f32x4 v = acc[mt];
                int p = __builtin_amdgcn_cvt_pk_fp8_f32(v[0] * FP8_SCALE, v[1] * FP8_SCALE, 0, 0);
                p = __builtin_amdgcn_cvt_pk_fp8_f32(v[2] * FP8_SCALE, v[3] * FP8_SCALE, p, 1);
                *(u32*)(rp + mt * 16) = (u32)p;
            }
        }

        #pragma unroll
        for (int j = 0; j < 8; ++j) cur[j] = nxt[j];
    }
}

// ---------------------------------------------------------------------------
// Gather+sum from fp8 tables -> rep (cur|prev, rescale + b1 folded).
// Block = 8 batch rows; t = sub(3b)|bag(2b)|lc(3b); thread = 16 B x 32 rows.
// ---------------------------------------------------------------------------
__global__ __launch_bounds__(256) void gather_rep(
    const int* __restrict__ diag, const int* __restrict__ proc,
    const int* __restrict__ pdiag, const int* __restrict__ pproc,
    const u8* __restrict__ Td, const u8* __restrict__ Tp,
    const float* __restrict__ b1, u16* __restrict__ rep)
{
    __shared__ int   sidx[8 * 4 * 33];       // [sub][bag][33]
    __shared__ float sred[8][2][8][16];      // [sub][half][lc][16] = 16 KB
    const int t = threadIdx.x;

    for (int i = t; i < 1024; i += 256) {
        const int s = i >> 7, bg = (i >> 5) & 3, l = i & 31;
        const int* cp = (bg == 0) ? diag : (bg == 1) ? proc : (bg == 2) ? pdiag : pproc;
        sidx[(s * 4 + bg) * 33 + l] = cp[(blockIdx.x * 8 + s) * 32 + l];
    }
    __syncthreads();

    const int sub = t >> 5, bag = (t >> 3) & 3, lc = t & 7;
    const u8* tbl = (bag & 1) ? Tp : Td;
    const int* myidx = &sidx[(sub * 4 + bag) * 33];

    f32x2 s[8];
    #pragma unroll
    for (int i = 0; i < 8; ++i) s[i] = (f32x2){0.f, 0.f};

    uint4 va[8], vb[8];
    #pragma unroll
    for (int j = 0; j < 8; ++j)
        va[j] = *(const uint4*)(tbl + (size_t)myidx[j] * 128 + lc * 16);
    #pragma unroll
    for (int j = 0; j < 8; ++j)
        vb[j] = *(const uint4*)(tbl + (size_t)myidx[8 + j] * 128 + lc * 16);

#define CONSUME(V) do { \
    _Pragma("unroll") \
    for (int j = 0; j < 8; ++j) { \
        s[0] += __builtin_amdgcn_cvt_pk_f32_fp8((int)V[j].x, 0); \
        s[1] += __builtin_amdgcn_cvt_pk_f32_fp8((int)V[j].x, 1); \
        s[2] += __builtin_amdgcn_cvt_pk_f32_fp8((int)V[j].y, 0); \
        s[3] += __builtin_amdgcn_cvt_pk_f32_fp8((int)V[j].y, 1); \
        s[4] += __builtin_amdgcn_cvt_pk_f32_fp8((int)V[j].z, 0); \
        s[5] += __builtin_amdgcn_cvt_pk_f32_fp8((int)V[j].z, 1); \
        s[6] += __builtin_amdgcn_cvt_pk_f32_fp8((int)V[j].w, 0); \
        s[7] += __builtin_amdgcn_cvt_pk_f32_fp8((int)V[j].w, 1); \
    } } while (0)

    {
        uint4 tmp[8];
        #pragma unroll
        for (int j = 0; j < 8; ++j)
            tmp[j] = *(const uint4*)(tbl + (size_t)myidx[16 + j] * 128 + lc * 16);
        CONSUME(va);
        #pragma unroll
        for (int j = 0; j < 8; ++j) va[j] = tmp[j];
    }
    {
        uint4 tmp[8];
        #pragma unroll
        for (int j = 0; j < 8; ++j)
            tmp[j] = *(const uint4*)(tbl + (size_t)myidx[24 + j] * 128 + lc * 16);
        CONSUME(vb);
        #pragma unroll
        for (int j = 0; j < 8; ++j) vb[j] = tmp[j];
    }
    CONSUME(va);
    CONSUME(vb);
#undef CONSUME

    const int half = bag >> 1;
    if (bag & 1) {
        float* dst = &sred[sub][half][lc][0];
        #pragma unroll
        for (int i = 0; i < 4; ++i)
            *(f32x4*)(dst + i * 4) = (f32x4){s[2*i].x, s[2*i].y, s[2*i+1].x, s[2*i+1].y};
    }
    __syncthreads();
    if (!(bag & 1)) {
        const float* par = &sred[sub][half][lc][0];
        const float* bp  = b1 + lc * 16;
        u32 o[8];
        #pragma unroll
        for (int i = 0; i < 8; ++i) {
            const float e0 = (s[i].x + par[2*i])   * FP8_INV + bp[2*i];
            const float e1 = (s[i].y + par[2*i+1]) * FP8_INV + bp[2*i+1];
            o[i] = (u32)f2bf(e0) | ((u32)f2bf(e1) << 16);
        }
        const int b = blockIdx.x * 8 + sub;
        u16* dst = rep + (size_t)b * 256 + half * 128 + lc * 16;
        *(uint4*)dst       = make_uint4(o[0], o[1], o[2], o[3]);
        *(uint4*)(dst + 8) = make_uint4(o[4], o[5], o[6], o[7]);
    }
}

// ---------------------------------------------------------------------------
// GEMM2: h = relu(rep @ W2^T + b2), bf16 out. W2-resident-in-registers:
// block = 64 N-cols x 128 M-rows, grid (4,128).
// ---------------------------------------------------------------------------
__global__ __launch_bounds__(256, 2) void gemm2(
    const u16* __restrict__ rep, const u16* __restrict__ W2b,
    const float* __restrict__ b2, u16* __restrict__ h)
{
    const int wave = threadIdx.x >> 6, lane = threadIdx.x & 63;
    const int quad = lane >> 4, l16 = lane & 15;
    const int nBase = blockIdx.x * 64;
    const int mChunk = blockIdx.y * 128;

    bf16x8 w[4][8];
    #pragma unroll
    for (int nt = 0; nt < 4; ++nt) {
        const u16* wP = W2b + (size_t)(nBase + nt * 16 + l16) * 256 + quad * 8;
        #pragma unroll
        for (int ks = 0; ks < 8; ++ks) w[nt][ks] = *(const bf16x8*)(wP + ks * 32);
    }
    float bv[4];
    #pragma unroll
    for (int nt = 0; nt < 4; ++nt) bv[nt] = b2[nBase + nt * 16 + l16];

    const u16* aP = rep + (size_t)(mChunk + wave * 16 + l16) * 256 + quad * 8;
    bf16x8 a[8];
    #pragma unroll
    for (int ks = 0; ks < 8; ++ks) a[ks] = *(const bf16x8*)(aP + ks * 32);

    #pragma unroll 1
    for (int iter = 0; iter < 2; ++iter) {
        bf16x8 an[8];
        if (iter < 1) {
            const u16* aN = aP + 64 * 256;
            #pragma unroll
            for (int ks = 0; ks < 8; ++ks) an[ks] = *(const bf16x8*)(aN + ks * 32);
        }
        f32x4 acc[4];
        #pragma unroll
        for (int nt = 0; nt < 4; ++nt) acc[nt] = (f32x4){0.f,0.f,0.f,0.f};
        #pragma unroll
        for (int ks = 0; ks < 8; ++ks)
            #pragma unroll
            for (int nt = 0; nt < 4; ++nt)
                acc[nt] = __builtin_amdgcn_mfma_f32_16x16x32_bf16(a[ks], w[nt][ks], acc[nt], 0, 0, 0);

        const int rowB = mChunk + iter * 64 + wave * 16 + quad * 4;
        #pragma unroll
        for (int nt = 0; nt < 4; ++nt) {
            const int col = nBase + nt * 16 + l16;
            #pragma unroll
            for (int r = 0; r < 4; ++r) {
                float v = acc[nt][r] + bv[nt];
                v = v > 0.f ? v : 0.f;
                h[(size_t)(rowB + r) * 256 + col] = f2bf(v);
            }
        }
        if (iter < 1) {
            aP += 64 * 256;
            #pragma unroll
            for (int ks = 0; ks < 8; ++ks) a[ks] = an[ks];
        }
    }
}

// ---------------------------------------------------------------------------
// GEMM3: out = sigmoid(h @ W3^T + b3), fp32 [16384,1000]. W3-resident:
// block = 64 N-cols x 512 M-rows, grid (16,32); 8 rolled M-iterations.
// ---------------------------------------------------------------------------
__global__ __launch_bounds__(256, 2) void gemm3(
    const u16* __restrict__ h, const u16* __restrict__ W3b,
    const float* __restrict__ b3, float* __restrict__ out)
{
    const int wave = threadIdx.x >> 6, lane = threadIdx.x & 63;
    const int quad = lane >> 4, l16 = lane & 15;
    const int nBase = blockIdx.x * 64;
    const int mChunk = blockIdx.y * 512;

    bf16x8 w[4][8];
    #pragma unroll
    for (int nt = 0; nt < 4; ++nt) {
        const u16* wP = W3b + (size_t)(nBase + nt * 16 + l16) * 256 + quad * 8;
        #pragma unroll
        for (int ks = 0; ks < 8; ++ks) w[nt][ks] = *(const bf16x8*)(wP + ks * 32);
    }
    float bv[4]; int colv[4];
    #pragma unroll
    for (int nt = 0; nt < 4; ++nt) {
        colv[nt] = nBase + nt * 16 + l16;
        bv[nt] = (colv[nt] < MED) ? b3[colv[nt]] : 0.f;
    }

    const u16* aP = h + (size_t)(mChunk + wave * 16 + l16) * 256 + quad * 8;
    bf16x8 a[8];
    #pragma unroll
    for (int ks = 0; ks < 8; ++ks) a[ks] = *(const bf16x8*)(aP + ks * 32);

    #pragma unroll 1
    for (int iter = 0; iter < 8; ++iter) {
        bf16x8 an[8];
        if (iter < 7) {
            const u16* aN = aP + 64 * 256;
            #pragma unroll
            for (int ks = 0; ks < 8; ++ks) an[ks] = *(const bf16x8*)(aN + ks * 32);
        }
        f32x4 acc[4];
        #pragma unroll
        for (int nt = 0; nt < 4; ++nt) acc[nt] = (f32x4){0.f,0.f,0.f,0.f};
        #pragma unroll
        for (int ks = 0; ks < 8; ++ks)
            #pragma unroll
            for (int nt = 0; nt < 4; ++nt)
                acc[nt] = __builtin_amdgcn_mfma_f32_16x16x32_bf16(a[ks], w[nt][ks], acc[nt], 0, 0, 0);

        const int rowB = mChunk + iter * 64 + wave * 16 + quad * 4;
        #pragma unroll
        for (int nt = 0; nt < 4; ++nt) {
            if (colv[nt] < MED) {
                #pragma unroll
                for (int r = 0; r < 4; ++r) {
                    const float v = acc[nt][r] + bv[nt];
                    const float e = __expf(-v);
                    out[(size_t)(rowB + r) * MED + colv[nt]] = __builtin_amdgcn_rcpf(1.0f + e);
                }
            }
        }
        if (iter < 7) {
            aP += 64 * 256;
            #pragma unroll
            for (int ks = 0; ks < 8; ++ks) a[ks] = an[ks];
        }
    }
}

// ---------------------------------------------------------------------------
extern "C" void kernel_launch(void* const* d_in, const int* in_sizes, int n_in,
                              void* d_out, int out_size, void* d_ws, size_t ws_size,
                              hipStream_t stream)
{
    const int*   diag  = (const int*)d_in[0];
    const int*   proc  = (const int*)d_in[1];
    const int*   pdiag = (const int*)d_in[2];
    const int*   pproc = (const int*)d_in[3];
    const float* demb  = (const float*)d_in[4];
    const float* pemb  = (const float*)d_in[5];
    const float* W1    = (const float*)d_in[6];
    const float* b1    = (const float*)d_in[7];
    const float* W2    = (const float*)d_in[8];
    const float* b2    = (const float*)d_in[9];
    const float* W3    = (const float*)d_in[10];
    const float* b3    = (const float*)d_in[11];

    char* ws = (char*)d_ws;
    // ws layout (bytes), total ~28.2 MB:
    //   Td  [100000,128] fp8  : 0          .. 12,800,000   (h aliases Td after gather)
    //   Tp  [ 50000,128] fp8  : 12,800,000 .. 19,200,000
    //   rep [16384,256]  bf16 : 19,200,000 .. 27,588,608
    //   W2b [256,256]    bf16 : 27,588,608 .. 27,719,680
    //   W3b [1024,256]   bf16 : 27,719,680 .. 28,243,968
    u8*  Td  = (u8*)ws;
    u8*  Tp  = (u8*)(ws + 12800000);
    u16* rep = (u16*)(ws + 19200000);
    u16* W2b = (u16*)(ws + 27588608);
    u16* W3b = (u16*)(ws + 27719680);
    u16* h   = (u16*)ws;               // aliases Td (dead after gather_rep)

    prep_kernel<<<TDB + TPB + NCV, 256, 0, stream>>>(demb, pemb, W1, W2, W3, Td, Tp, W2b, W3b);
    gather_rep<<<NB / 8, 256, 0, stream>>>(diag, proc, pdiag, pproc, Td, Tp, b1, rep);
    gemm2<<<dim3(4, 128), 256, 0, stream>>>(rep, W2b, b2, h);
    gemm3<<<dim3(16, 32), 256, 0, stream>>>(h, W3b, b3, (float*)d_out);
}